// Round 8
// baseline (257.282 us; speedup 1.0000x reference)
//
#include <hip/hip_runtime.h>
#include <math.h>

// QuadraticAttention on MI355X — round 8: attention K/V double-buffer prefetch.
// r7 evidence: occupancy 11->19% changed nothing; makespan = critical block's
// serial chain (~5.5k cyc/iter), dominated by the barrier-coupled cp16 drain
// (loads issued at the barrier, consumed right after). Now: prefetch tile
// kt+1 into the other buffer right after the barrier that publishes tile kt
// -> loads overlap compute; 1 barrier/iter. Q-frags hoisted to registers.
// GEMMs/cvt unchanged.

typedef float  f32x4  __attribute__((ext_vector_type(4)));
typedef short  bf16x8 __attribute__((ext_vector_type(8)));
typedef float  vf4    __attribute__((ext_vector_type(4)));
typedef unsigned short u16x4 __attribute__((ext_vector_type(4)));

static __device__ __forceinline__ unsigned short f2bf(float f) {
    union { float f; unsigned int i; } c; c.f = f;
    unsigned int x = c.i;
    return (unsigned short)((x + 0x7fffu + ((x >> 16) & 1u)) >> 16);
}
static __device__ __forceinline__ f32x4 shfl_xor4(f32x4 v, int m) {
    f32x4 r;
    r[0] = __shfl_xor(v[0], m); r[1] = __shfl_xor(v[1], m);
    r[2] = __shfl_xor(v[2], m); r[3] = __shfl_xor(v[3], m);
    return r;
}
static __device__ __forceinline__ f32x4 rsq4(f32x4 v) {
    f32x4 r;
#pragma unroll
    for (int i = 0; i < 4; i++) r[i] = rsqrtf(v[i] * (1.0f / 64.0f) + 1.1920929e-07f);
    return r;
}
// async 16B/lane global -> LDS (wave-uniform LDS base + lane*16)
static __device__ __forceinline__ void cp16(const unsigned short* g, unsigned short* l) {
    __builtin_amdgcn_global_load_lds(
        (const __attribute__((address_space(1))) unsigned int*)g,
        (__attribute__((address_space(3))) unsigned int*)l, 16, 0, 0);
}

#define FOR_M(X)  X(0) X(1) X(2) X(3)
#define FOR_MN(X) X(0,0) X(0,1) X(0,2) X(0,3) X(1,0) X(1,1) X(1,2) X(1,3) \
                  X(2,0) X(2,1) X(2,2) X(2,3) X(3,0) X(3,1) X(3,2) X(3,3)

// ---------------------------------------------------------------------------
// fused fp32->bf16 conversion for x + 4 weight matrices (1 launch)
// ---------------------------------------------------------------------------
__global__ __launch_bounds__(256) void cvt_all(
    const float* __restrict__ x,  const float* __restrict__ Wq,
    const float* __restrict__ Wk, const float* __restrict__ Wv,
    const float* __restrict__ Wo,
    unsigned short* __restrict__ xb,  unsigned short* __restrict__ Wqb,
    unsigned short* __restrict__ Wkb, unsigned short* __restrict__ Wvb,
    unsigned short* __restrict__ Wob, int nx4, int nw4)
{
    int i = blockIdx.x * 256 + threadIdx.x;
    const float* s; unsigned short* d; int li;
    if (i < nx4) { s = x; d = xb; li = i; }
    else {
        int idx = i - nx4;
        int r = idx / nw4; li = idx - r * nw4;
        if (r >= 4) return;
        s = (r == 0) ? Wq : (r == 1) ? Wk : (r == 2) ? Wv : Wo;
        d = (r == 0) ? Wqb : (r == 1) ? Wkb : (r == 2) ? Wvb : Wob;
    }
    vf4 v = *(const vf4*)(s + (size_t)li * 4);
    u16x4 o;
#pragma unroll
    for (int j = 0; j < 4; j++) o[j] = f2bf(v[j]);
    *(u16x4*)(d + (size_t)li * 4) = o;
}

// ---------------------------------------------------------------------------
#define SS 136   // epilogue stage row stride (elems)

// GEMM-core macros; LDS tiles are unpadded [128][32] (row = 64 B)
#define G_DECL_ACC(mi,ni) f32x4 c##mi##ni = {0.f, 0.f, 0.f, 0.f};
#define G_DECL_A(mi) bf16x8 a##mi = *(const bf16x8*)&As[(wy * 64 + (mi) * 16 + l15) * 32 + quad * 8];
#define G_DECL_B(ni) bf16x8 b##ni = *(const bf16x8*)&Ws[(wx * 64 + (ni) * 16 + l15) * 32 + quad * 8];
#define G_MFMA(mi,ni) c##mi##ni = __builtin_amdgcn_mfma_f32_16x16x32_bf16(a##mi, b##ni, c##mi##ni, 0, 0, 0);

__global__ __launch_bounds__(256) void gemm_qkv(
    const unsigned short* __restrict__ xb,
    const unsigned short* __restrict__ Wqb,
    const unsigned short* __restrict__ Wkb,
    const unsigned short* __restrict__ Wvb,
    const float* __restrict__ bqf, const float* __restrict__ bkf, const float* __restrict__ bvf,
    const float* __restrict__ nwp,
    unsigned short* __restrict__ qb, unsigned short* __restrict__ kb,
    unsigned short* __restrict__ vT, int M)
{
    const int K = 1024;
    __shared__ unsigned short smem[128 * SS];   // 34816 B; [As|Ws] then stage
    unsigned short* As = smem;                  // 128*32 = 4096 elems
    unsigned short* Ws = smem + 4096;
    const int tid = threadIdx.x;
    const int z = blockIdx.z;
    const unsigned short* Wb = (z == 0) ? Wqb : (z == 1) ? Wkb : Wvb;
    const float* bias = (z == 0) ? bqf : (z == 1) ? bkf : bvf;
    const int n0 = blockIdx.x * 128;
    const int m0 = blockIdx.y * 128;
    const int lane = tid & 63, wid = tid >> 6;
    const int wy = wid >> 1, wx = wid & 1;
    const int l15 = lane & 15, quad = lane >> 4;
    const int r16 = lane >> 2;          // staging: row within 16-row chunk
    const int c8  = (lane & 3) * 8;     // staging: elem offset within row

    FOR_MN(G_DECL_ACC)

    for (int kt = 0; kt < K; kt += 32) {
        __syncthreads();
#pragma unroll
        for (int j = 0; j < 2; j++) {
            const int ch = wid * 2 + j;               // 0..7, 16 rows each
            const int row = ch * 16 + r16;
            cp16(xb + (size_t)(m0 + row) * K + kt + c8, &As[ch * 512]);
            cp16(Wb + (size_t)(n0 + row) * K + kt + c8, &Ws[ch * 512]);
        }
        __syncthreads();
        FOR_M(G_DECL_A)
        FOR_M(G_DECL_B)
        FOR_MN(G_MFMA)
    }
    __syncthreads();   // MFMA LDS reads done before smem reused as stage

    // ---- epilogue ----
#define G_DECL_BIAS(ni) float bs##ni = bias[n0 + wx * 64 + (ni) * 16 + l15]; \
                        float nww##ni = nwp[(ni) * 16 + l15];
    FOR_M(G_DECL_BIAS)
#define G_ADD_BIAS(mi,ni) c##mi##ni = c##mi##ni + bs##ni;
    FOR_MN(G_ADD_BIAS)

    if (z < 2) {
#define G_SUMSQ(mi) f32x4 s2_##mi = c##mi##0 * c##mi##0 + c##mi##1 * c##mi##1 + \
                                    c##mi##2 * c##mi##2 + c##mi##3 * c##mi##3;
        FOR_M(G_SUMSQ)
#define G_RED(mi) s2_##mi = s2_##mi + shfl_xor4(s2_##mi, 1); \
                  s2_##mi = s2_##mi + shfl_xor4(s2_##mi, 2); \
                  s2_##mi = s2_##mi + shfl_xor4(s2_##mi, 4); \
                  s2_##mi = s2_##mi + shfl_xor4(s2_##mi, 8); \
                  s2_##mi = rsq4(s2_##mi);
        FOR_M(G_RED)

        const float lf0 = expf(-(float)l15 * 0.28782313662425572f);          // ln(1e4)/32
        const float lf1 = expf(-(float)(l15 + 16) * 0.28782313662425572f);

#define G_ROPE_ONE(mi,ni,CS,SN) { \
            float vn = c##mi##ni[r] * s2v[r] * nww##ni; \
            float pt = __shfl_xor(vn, 1); \
            float rot = (lane & 1) ? pt : -pt; \
            smem[mrow * SS + wx * 64 + (ni) * 16 + l15] = f2bf(vn * (CS) + rot * (SN)); }
#define G_ROPE_MI(mi) { f32x4 s2v = s2_##mi; \
            _Pragma("unroll") \
            for (int r = 0; r < 4; r++) { \
                const int mrow = wy * 64 + (mi) * 16 + quad * 4 + r; \
                const float t = (float)((m0 + mrow) & 2047); \
                const float a0 = t * lf0, a1 = t * lf1; \
                const float cs0 = cosf(a0), sn0 = sinf(a0); \
                const float cs1 = cosf(a1), sn1 = sinf(a1); \
                G_ROPE_ONE(mi,0,cs0,sn0) G_ROPE_ONE(mi,1,cs1,sn1) \
                G_ROPE_ONE(mi,2,cs0,sn0) G_ROPE_ONE(mi,3,cs1,sn1) } }
        FOR_M(G_ROPE_MI)

        __syncthreads();
        unsigned short* dst = (z == 0) ? qb : kb;
#pragma unroll
        for (int it = 0; it < 8; it++) {
            const int linear = tid + it * 256;
            const int row = linear >> 4, cb = linear & 15;
            *(bf16x8*)(dst + (size_t)(m0 + row) * 1024 + n0 + cb * 8) =
                *(const bf16x8*)&smem[row * SS + cb * 8];
        }
    } else {
#define G_VST(mi,ni) { _Pragma("unroll") \
            for (int r = 0; r < 4; r++) { \
                const int mrow = wy * 64 + (mi) * 16 + quad * 4 + r; \
                smem[(wx * 64 + (ni) * 16 + l15) * SS + mrow] = f2bf(c##mi##ni[r]); } }
        FOR_MN(G_VST)
        __syncthreads();
        const int b = m0 >> 11, tok0 = m0 & 2047;
#pragma unroll
        for (int it = 0; it < 8; it++) {
            const int linear = tid + it * 256;
            const int rowd = linear >> 4, cb = linear & 15;
            const int head_g = (n0 >> 6) + (rowd >> 6);
            const int d = rowd & 63;
            *(bf16x8*)(vT + (((size_t)b * 16 + head_g) * 64 + d) * 2048 + tok0 + cb * 8) =
                *(const bf16x8*)&smem[rowd * SS + cb * 8];
        }
    }
}

// ---------------------------------------------------------------------------
__global__ __launch_bounds__(256) void gemm_out(
    const unsigned short* __restrict__ zb,
    const unsigned short* __restrict__ Wob,
    const float* __restrict__ x, float* __restrict__ out, int M)
{
    const int K = 1024;
    __shared__ unsigned short As[4096];
    __shared__ unsigned short Ws[4096];
    const int tid = threadIdx.x;
    const int n0 = blockIdx.x * 128;
    const int m0 = blockIdx.y * 128;
    const int lane = tid & 63, wid = tid >> 6;
    const int wy = wid >> 1, wx = wid & 1;
    const int l15 = lane & 15, quad = lane >> 4;
    const int r16 = lane >> 2;
    const int c8  = (lane & 3) * 8;

    FOR_MN(G_DECL_ACC)

    for (int kt = 0; kt < K; kt += 32) {
        __syncthreads();
#pragma unroll
        for (int j = 0; j < 2; j++) {
            const int ch = wid * 2 + j;
            const int row = ch * 16 + r16;
            cp16(zb + (size_t)(m0 + row) * K + kt + c8, &As[ch * 512]);
            cp16(Wob + (size_t)(n0 + row) * K + kt + c8, &Ws[ch * 512]);
        }
        __syncthreads();
        FOR_M(G_DECL_A)
        FOR_M(G_DECL_B)
        FOR_MN(G_MFMA)
    }

#define G_OUTST(mi,ni) { _Pragma("unroll") \
        for (int r = 0; r < 4; r++) { \
            const int m = m0 + wy * 64 + (mi) * 16 + quad * 4 + r; \
            const int n = n0 + wx * 64 + (ni) * 16 + l15; \
            out[(size_t)m * 1024 + n] = c##mi##ni[r] + x[(size_t)m * 1024 + n]; } }
    FOR_MN(G_OUTST)
}

// ---------------------------------------------------------------------------
// Causal quadratic attention, double-buffered. Block = 64 q-rows of one
// (b,h); wave w owns 16 q-rows; Q-frags hoisted to registers. Per iteration:
// one barrier publishes tile kt, then tile kt+1's cp16s are issued into the
// other buffer (in flight during compute). Pm per-wave (no barrier).
// ---------------------------------------------------------------------------
__global__ __launch_bounds__(256) void attn_mfma(
    const unsigned short* __restrict__ qb, const unsigned short* __restrict__ kb,
    const unsigned short* __restrict__ vT, unsigned short* __restrict__ zb)
{
    __shared__ unsigned short Qs[4096];       // [2 halves][64][32]
    __shared__ unsigned short Kb[2][4096];    // dbuf, each [2][64][32]
    __shared__ unsigned short Vb[2][4096];    // dbuf (rows = d)
    __shared__ unsigned short Pm[64 * 72];
    const int tid = threadIdx.x;
    const int qt = 31 - blockIdx.x;           // 0..31, big tiles first
    const int bh = blockIdx.y;
    const int b = bh >> 4, h = bh & 15;
    const int lane = tid & 63, wq = tid >> 6;
    const int l15 = lane & 15, quad = lane >> 4;
    const int r16 = lane >> 2;
    const int c8  = (lane & 3) * 8;
    const size_t tokbase = (size_t)b * 2048;
    const int q0 = qt * 64;

    // stage Q (8 chunks of 16 rows, half-split)
#pragma unroll
    for (int j = 0; j < 2; j++) {
        const int ch = wq * 2 + j;
        const int half = ch >> 2;
        const int row = (ch & 3) * 16 + r16;
        cp16(qb + (tokbase + q0 + row) * 1024 + h * 64 + half * 32 + c8, &Qs[ch * 512]);
    }
    __syncthreads();   // Q published
    const bf16x8 aq0 = *(const bf16x8*)&Qs[(wq * 16 + l15) * 32 + quad * 8];
    const bf16x8 aq1 = *(const bf16x8*)&Qs[2048 + (wq * 16 + l15) * 32 + quad * 8];

    // prefetch K/V tile 0 into buffer 0
#pragma unroll
    for (int j = 0; j < 2; j++) {
        const int ch = wq * 2 + j;
        const int half = ch >> 2;
        const int row = (ch & 3) * 16 + r16;
        cp16(kb + (tokbase + row) * 1024 + h * 64 + half * 32 + c8, &Kb[0][ch * 512]);
        cp16(vT + ((size_t)bh * 64 + row) * 2048 + half * 32 + c8, &Vb[0][ch * 512]);
    }

#define A_DECL_Z(n) f32x4 z_##n = {0.f, 0.f, 0.f, 0.f};
    FOR_M(A_DECL_Z)

    const int nkt = qt + 1;
    for (int kt = 0; kt < nkt; kt++) {
        __syncthreads();                       // publishes tile kt (drains cp16)
        const int p = kt & 1;
        if (kt + 1 < nkt) {                    // prefetch kt+1 into other buffer
            const int np = p ^ 1;
#pragma unroll
            for (int j = 0; j < 2; j++) {
                const int ch = wq * 2 + j;
                const int half = ch >> 2;
                const int row = (ch & 3) * 16 + r16;
                cp16(kb + (tokbase + (kt + 1) * 64 + row) * 1024 + h * 64 + half * 32 + c8,
                     &Kb[np][ch * 512]);
                cp16(vT + ((size_t)bh * 64 + row) * 2048 + (kt + 1) * 64 + half * 32 + c8,
                     &Vb[np][ch * 512]);
            }
        }
        const unsigned short* Kp = Kb[p];
        const unsigned short* Vp = Vb[p];

        // S = Q K^T : wave computes 16 q-rows x 64 k-cols
#define A_DECL_S(n) f32x4 s_##n = {0.f, 0.f, 0.f, 0.f};
        FOR_M(A_DECL_S)
#define A_SHALF(KS, AQ) { \
        bf16x8 t0 = *(const bf16x8*)&Kp[(KS) * 2048 + (l15) * 32 + quad * 8]; \
        bf16x8 t1 = *(const bf16x8*)&Kp[(KS) * 2048 + (16 + l15) * 32 + quad * 8]; \
        bf16x8 t2 = *(const bf16x8*)&Kp[(KS) * 2048 + (32 + l15) * 32 + quad * 8]; \
        bf16x8 t3 = *(const bf16x8*)&Kp[(KS) * 2048 + (48 + l15) * 32 + quad * 8]; \
        s_0 = __builtin_amdgcn_mfma_f32_16x16x32_bf16(AQ, t0, s_0, 0, 0, 0); \
        s_1 = __builtin_amdgcn_mfma_f32_16x16x32_bf16(AQ, t1, s_1, 0, 0, 0); \
        s_2 = __builtin_amdgcn_mfma_f32_16x16x32_bf16(AQ, t2, s_2, 0, 0, 0); \
        s_3 = __builtin_amdgcn_mfma_f32_16x16x32_bf16(AQ, t3, s_3, 0, 0, 0); }
        A_SHALF(0, aq0)
        A_SHALF(1, aq1)

        // P = (S/64)^2, causal mask only on the diagonal tile
        const bool needmask = (kt == qt);
#define A_PSTORE(n) { \
        f32x4 p4 = (s_##n * s_##n) * (1.0f / 4096.0f); \
        if (needmask) { _Pragma("unroll") \
            for (int r = 0; r < 4; r++) \
                if (kt * 64 + (n) * 16 + l15 > q0 + wq * 16 + quad * 4 + r) p4[r] = 0.f; } \
        _Pragma("unroll") \
        for (int r = 0; r < 4; r++) \
            Pm[(wq * 16 + quad * 4 + r) * 72 + (n) * 16 + l15] = f2bf(p4[r]); }
        FOR_M(A_PSTORE)

        // Z += P @ V  (A = wave's Pm rows; B from Vt tile)
#define A_PVHALF(KS) { \
        bf16x8 ap = *(const bf16x8*)&Pm[(wq * 16 + l15) * 72 + (KS) * 32 + quad * 8]; \
        bf16x8 u0 = *(const bf16x8*)&Vp[(KS) * 2048 + (l15) * 32 + quad * 8]; \
        bf16x8 u1 = *(const bf16x8*)&Vp[(KS) * 2048 + (16 + l15) * 32 + quad * 8]; \
        bf16x8 u2 = *(const bf16x8*)&Vp[(KS) * 2048 + (32 + l15) * 32 + quad * 8]; \
        bf16x8 u3 = *(const bf16x8*)&Vp[(KS) * 2048 + (48 + l15) * 32 + quad * 8]; \
        z_0 = __builtin_amdgcn_mfma_f32_16x16x32_bf16(ap, u0, z_0, 0, 0, 0); \
        z_1 = __builtin_amdgcn_mfma_f32_16x16x32_bf16(ap, u1, z_1, 0, 0, 0); \
        z_2 = __builtin_amdgcn_mfma_f32_16x16x32_bf16(ap, u2, z_2, 0, 0, 0); \
        z_3 = __builtin_amdgcn_mfma_f32_16x16x32_bf16(ap, u3, z_3, 0, 0, 0); }
        A_PVHALF(0)
        A_PVHALF(1)
    }

    // stage z into wave-private Pm rows, then 16B contiguous stores
#define A_ZST(n) { _Pragma("unroll") \
        for (int r = 0; r < 4; r++) \
            Pm[(wq * 16 + quad * 4 + r) * 72 + (n) * 16 + l15] = f2bf(z_##n[r]); }
    FOR_M(A_ZST)
#pragma unroll
    for (int it = 0; it < 2; it++) {
        const int linear = it * 64 + lane;
        const int row = linear >> 3, cb = linear & 7;   // 16 rows x 8 segs
        *(bf16x8*)(zb + (tokbase + q0 + wq * 16 + row) * 1024 + h * 64 + cb * 8) =
            *(const bf16x8*)&Pm[(wq * 16 + row) * 72 + cb * 8];
    }
}

// ---------------------------------------------------------------------------
extern "C" void kernel_launch(void* const* d_in, const int* in_sizes, int n_in,
                              void* d_out, int out_size, void* d_ws, size_t ws_size,
                              hipStream_t stream)
{
    const float* x  = (const float*)d_in[0];
    const float* Wq = (const float*)d_in[1];
    const float* bq = (const float*)d_in[2];
    const float* Wk = (const float*)d_in[3];
    const float* bk = (const float*)d_in[4];
    const float* Wv = (const float*)d_in[5];
    const float* bv = (const float*)d_in[6];
    const float* Wo = (const float*)d_in[7];
    const float* nw = (const float*)d_in[8];
    float* out = (float*)d_out;

    const int D = 1024;
    const int M = in_sizes[0] / D;   // B*S = 4096

    unsigned short* xbb = (unsigned short*)d_ws;         // M*D
    unsigned short* Wqb = xbb + (size_t)M * D;           // D*D
    unsigned short* Wkb = Wqb + (size_t)D * D;
    unsigned short* Wvb = Wkb + (size_t)D * D;
    unsigned short* Wob = Wvb + (size_t)D * D;
    unsigned short* qbw = Wob + (size_t)D * D;           // M*D
    unsigned short* kbw = qbw + (size_t)M * D;
    unsigned short* vTw = kbw + (size_t)M * D;
    unsigned short* zbw = vTw + (size_t)M * D;

    const int nx4 = M * D / 4, nw4 = D * D / 4;
    const int ncvt = nx4 + 4 * nw4;
    cvt_all<<<(ncvt + 255) / 256, 256, 0, stream>>>(
        x, Wq, Wk, Wv, Wo, xbb, Wqb, Wkb, Wvb, Wob, nx4, nw4);

    gemm_qkv<<<dim3(D / 128, M / 128, 3), 256, 0, stream>>>(
        xbb, Wqb, Wkb, Wvb, bq, bk, bv, nw, qbw, kbw, vTw, M);

    attn_mfma<<<dim3(32, (M / 2048) * 16), 256, 0, stream>>>(qbw, kbw, vTw, zbw);

    gemm_out<<<dim3(D / 128, M / 128), 256, 0, stream>>>(zbw, Wob, x, out, M);
}

// Round 9
// 239.451 us; speedup vs baseline: 1.0745x; 1.0745x over previous
//
#include <hip/hip_runtime.h>
#include <math.h>

// QuadraticAttention on MI355X — round 9: attn rewrite — conflict-free padded
// LDS (stride 72) via reg-staged ds_write_b128 (cp16 dropped in attn: its
// lane-contiguous layout forced 64B rows => 8-way conflicts on every frag
// read; 5.4M conflict cycles in r7/r8). 128-row q-tiles, 32 q-rows/wave
// (2x MFMA per LDS byte), register K/V prefetch, q/k pre-scaled by 1/8
// (exact) so P = S^2 with no per-iter scaling. GEMMs/cvt unchanged.

typedef float  f32x4  __attribute__((ext_vector_type(4)));
typedef short  bf16x8 __attribute__((ext_vector_type(8)));
typedef float  vf4    __attribute__((ext_vector_type(4)));
typedef unsigned short u16x4 __attribute__((ext_vector_type(4)));

static __device__ __forceinline__ unsigned short f2bf(float f) {
    union { float f; unsigned int i; } c; c.f = f;
    unsigned int x = c.i;
    return (unsigned short)((x + 0x7fffu + ((x >> 16) & 1u)) >> 16);
}
static __device__ __forceinline__ f32x4 shfl_xor4(f32x4 v, int m) {
    f32x4 r;
    r[0] = __shfl_xor(v[0], m); r[1] = __shfl_xor(v[1], m);
    r[2] = __shfl_xor(v[2], m); r[3] = __shfl_xor(v[3], m);
    return r;
}
static __device__ __forceinline__ f32x4 rsq4(f32x4 v) {
    f32x4 r;
#pragma unroll
    for (int i = 0; i < 4; i++) r[i] = rsqrtf(v[i] * (1.0f / 64.0f) + 1.1920929e-07f);
    return r;
}
// async 16B/lane global -> LDS (GEMMs only)
static __device__ __forceinline__ void cp16(const unsigned short* g, unsigned short* l) {
    __builtin_amdgcn_global_load_lds(
        (const __attribute__((address_space(1))) unsigned int*)g,
        (__attribute__((address_space(3))) unsigned int*)l, 16, 0, 0);
}

#define FOR_M(X)  X(0) X(1) X(2) X(3)
#define FOR_MN(X) X(0,0) X(0,1) X(0,2) X(0,3) X(1,0) X(1,1) X(1,2) X(1,3) \
                  X(2,0) X(2,1) X(2,2) X(2,3) X(3,0) X(3,1) X(3,2) X(3,3)
#define FOR_MN2(X) X(0,0) X(0,1) X(0,2) X(0,3) X(1,0) X(1,1) X(1,2) X(1,3)

// ---------------------------------------------------------------------------
__global__ __launch_bounds__(256) void cvt_all(
    const float* __restrict__ x,  const float* __restrict__ Wq,
    const float* __restrict__ Wk, const float* __restrict__ Wv,
    const float* __restrict__ Wo,
    unsigned short* __restrict__ xb,  unsigned short* __restrict__ Wqb,
    unsigned short* __restrict__ Wkb, unsigned short* __restrict__ Wvb,
    unsigned short* __restrict__ Wob, int nx4, int nw4)
{
    int i = blockIdx.x * 256 + threadIdx.x;
    const float* s; unsigned short* d; int li;
    if (i < nx4) { s = x; d = xb; li = i; }
    else {
        int idx = i - nx4;
        int r = idx / nw4; li = idx - r * nw4;
        if (r >= 4) return;
        s = (r == 0) ? Wq : (r == 1) ? Wk : (r == 2) ? Wv : Wo;
        d = (r == 0) ? Wqb : (r == 1) ? Wkb : (r == 2) ? Wvb : Wob;
    }
    vf4 v = *(const vf4*)(s + (size_t)li * 4);
    u16x4 o;
#pragma unroll
    for (int j = 0; j < 4; j++) o[j] = f2bf(v[j]);
    *(u16x4*)(d + (size_t)li * 4) = o;
}

// ---------------------------------------------------------------------------
#define SS 136   // epilogue stage row stride (elems)

#define G_DECL_ACC(mi,ni) f32x4 c##mi##ni = {0.f, 0.f, 0.f, 0.f};
#define G_DECL_A(mi) bf16x8 a##mi = *(const bf16x8*)&As[(wy * 64 + (mi) * 16 + l15) * 32 + quad * 8];
#define G_DECL_B(ni) bf16x8 b##ni = *(const bf16x8*)&Ws[(wx * 64 + (ni) * 16 + l15) * 32 + quad * 8];
#define G_MFMA(mi,ni) c##mi##ni = __builtin_amdgcn_mfma_f32_16x16x32_bf16(a##mi, b##ni, c##mi##ni, 0, 0, 0);

__global__ __launch_bounds__(256) void gemm_qkv(
    const unsigned short* __restrict__ xb,
    const unsigned short* __restrict__ Wqb,
    const unsigned short* __restrict__ Wkb,
    const unsigned short* __restrict__ Wvb,
    const float* __restrict__ bqf, const float* __restrict__ bkf, const float* __restrict__ bvf,
    const float* __restrict__ nwp,
    unsigned short* __restrict__ qb, unsigned short* __restrict__ kb,
    unsigned short* __restrict__ vT, int M)
{
    const int K = 1024;
    __shared__ unsigned short smem[128 * SS];
    unsigned short* As = smem;
    unsigned short* Ws = smem + 4096;
    const int tid = threadIdx.x;
    const int z = blockIdx.z;
    const unsigned short* Wb = (z == 0) ? Wqb : (z == 1) ? Wkb : Wvb;
    const float* bias = (z == 0) ? bqf : (z == 1) ? bkf : bvf;
    const int n0 = blockIdx.x * 128;
    const int m0 = blockIdx.y * 128;
    const int lane = tid & 63, wid = tid >> 6;
    const int wy = wid >> 1, wx = wid & 1;
    const int l15 = lane & 15, quad = lane >> 4;
    const int r16 = lane >> 2;
    const int c8  = (lane & 3) * 8;

    FOR_MN(G_DECL_ACC)

    for (int kt = 0; kt < K; kt += 32) {
        __syncthreads();
#pragma unroll
        for (int j = 0; j < 2; j++) {
            const int ch = wid * 2 + j;
            const int row = ch * 16 + r16;
            cp16(xb + (size_t)(m0 + row) * K + kt + c8, &As[ch * 512]);
            cp16(Wb + (size_t)(n0 + row) * K + kt + c8, &Ws[ch * 512]);
        }
        __syncthreads();
        FOR_M(G_DECL_A)
        FOR_M(G_DECL_B)
        FOR_MN(G_MFMA)
    }
    __syncthreads();

#define G_DECL_BIAS(ni) float bs##ni = bias[n0 + wx * 64 + (ni) * 16 + l15]; \
                        float nww##ni = nwp[(ni) * 16 + l15];
    FOR_M(G_DECL_BIAS)
#define G_ADD_BIAS(mi,ni) c##mi##ni = c##mi##ni + bs##ni;
    FOR_MN(G_ADD_BIAS)

    if (z < 2) {
#define G_SUMSQ(mi) f32x4 s2_##mi = c##mi##0 * c##mi##0 + c##mi##1 * c##mi##1 + \
                                    c##mi##2 * c##mi##2 + c##mi##3 * c##mi##3;
        FOR_M(G_SUMSQ)
#define G_RED(mi) s2_##mi = s2_##mi + shfl_xor4(s2_##mi, 1); \
                  s2_##mi = s2_##mi + shfl_xor4(s2_##mi, 2); \
                  s2_##mi = s2_##mi + shfl_xor4(s2_##mi, 4); \
                  s2_##mi = s2_##mi + shfl_xor4(s2_##mi, 8); \
                  s2_##mi = rsq4(s2_##mi);
        FOR_M(G_RED)

        const float lf0 = expf(-(float)l15 * 0.28782313662425572f);          // ln(1e4)/32
        const float lf1 = expf(-(float)(l15 + 16) * 0.28782313662425572f);

        // NOTE: x0.125 (exact) folds the attention 1/64 score scale into q,k.
#define G_ROPE_ONE(mi,ni,CS,SN) { \
            float vn = c##mi##ni[r] * s2v[r] * nww##ni; \
            float pt = __shfl_xor(vn, 1); \
            float rot = (lane & 1) ? pt : -pt; \
            smem[mrow * SS + wx * 64 + (ni) * 16 + l15] = f2bf((vn * (CS) + rot * (SN)) * 0.125f); }
#define G_ROPE_MI(mi) { f32x4 s2v = s2_##mi; \
            _Pragma("unroll") \
            for (int r = 0; r < 4; r++) { \
                const int mrow = wy * 64 + (mi) * 16 + quad * 4 + r; \
                const float t = (float)((m0 + mrow) & 2047); \
                const float a0 = t * lf0, a1 = t * lf1; \
                const float cs0 = cosf(a0), sn0 = sinf(a0); \
                const float cs1 = cosf(a1), sn1 = sinf(a1); \
                G_ROPE_ONE(mi,0,cs0,sn0) G_ROPE_ONE(mi,1,cs1,sn1) \
                G_ROPE_ONE(mi,2,cs0,sn0) G_ROPE_ONE(mi,3,cs1,sn1) } }
        FOR_M(G_ROPE_MI)

        __syncthreads();
        unsigned short* dst = (z == 0) ? qb : kb;
#pragma unroll
        for (int it = 0; it < 8; it++) {
            const int linear = tid + it * 256;
            const int row = linear >> 4, cb = linear & 15;
            *(bf16x8*)(dst + (size_t)(m0 + row) * 1024 + n0 + cb * 8) =
                *(const bf16x8*)&smem[row * SS + cb * 8];
        }
    } else {
#define G_VST(mi,ni) { _Pragma("unroll") \
            for (int r = 0; r < 4; r++) { \
                const int mrow = wy * 64 + (mi) * 16 + quad * 4 + r; \
                smem[(wx * 64 + (ni) * 16 + l15) * SS + mrow] = f2bf(c##mi##ni[r]); } }
        FOR_MN(G_VST)
        __syncthreads();
        const int b = m0 >> 11, tok0 = m0 & 2047;
#pragma unroll
        for (int it = 0; it < 8; it++) {
            const int linear = tid + it * 256;
            const int rowd = linear >> 4, cb = linear & 15;
            const int head_g = (n0 >> 6) + (rowd >> 6);
            const int d = rowd & 63;
            *(bf16x8*)(vT + (((size_t)b * 16 + head_g) * 64 + d) * 2048 + tok0 + cb * 8) =
                *(const bf16x8*)&smem[rowd * SS + cb * 8];
        }
    }
}

// ---------------------------------------------------------------------------
__global__ __launch_bounds__(256) void gemm_out(
    const unsigned short* __restrict__ zb,
    const unsigned short* __restrict__ Wob,
    const float* __restrict__ x, float* __restrict__ out, int M)
{
    const int K = 1024;
    __shared__ unsigned short As[4096];
    __shared__ unsigned short Ws[4096];
    const int tid = threadIdx.x;
    const int n0 = blockIdx.x * 128;
    const int m0 = blockIdx.y * 128;
    const int lane = tid & 63, wid = tid >> 6;
    const int wy = wid >> 1, wx = wid & 1;
    const int l15 = lane & 15, quad = lane >> 4;
    const int r16 = lane >> 2;
    const int c8  = (lane & 3) * 8;

    FOR_MN(G_DECL_ACC)

    for (int kt = 0; kt < K; kt += 32) {
        __syncthreads();
#pragma unroll
        for (int j = 0; j < 2; j++) {
            const int ch = wid * 2 + j;
            const int row = ch * 16 + r16;
            cp16(zb + (size_t)(m0 + row) * K + kt + c8, &As[ch * 512]);
            cp16(Wob + (size_t)(n0 + row) * K + kt + c8, &Ws[ch * 512]);
        }
        __syncthreads();
        FOR_M(G_DECL_A)
        FOR_M(G_DECL_B)
        FOR_MN(G_MFMA)
    }

#define G_OUTST(mi,ni) { _Pragma("unroll") \
        for (int r = 0; r < 4; r++) { \
            const int m = m0 + wy * 64 + (mi) * 16 + quad * 4 + r; \
            const int n = n0 + wx * 64 + (ni) * 16 + l15; \
            out[(size_t)m * 1024 + n] = c##mi##ni[r] + x[(size_t)m * 1024 + n]; } }
    FOR_MN(G_OUTST)
}

// ---------------------------------------------------------------------------
// Causal quadratic attention, round 9.
// Block = 128 q-rows of one (b,h); wave w owns 32 q-rows (mi=0,1).
// K/V: coalesced global->reg prefetch, ds_write_b128 into padded [64][72]
// (stride 36 dw -> uniform banks, conflict-free). Q staged once, frags in
// regs. P roundtrip via per-wave Pm rows (stride 72). P = S^2 (q,k carry 1/8).
// ---------------------------------------------------------------------------
__global__ __launch_bounds__(256) void attn_mfma(
    const unsigned short* __restrict__ qb, const unsigned short* __restrict__ kb,
    const unsigned short* __restrict__ vT, unsigned short* __restrict__ zb)
{
    __shared__ unsigned short Qs[128 * 72];
    __shared__ unsigned short Ks[64 * 72];
    __shared__ unsigned short Vs[64 * 72];   // rows = d, cols = k-token
    __shared__ unsigned short Pm[128 * 72];
    const int tid = threadIdx.x;
    const int qt = 15 - blockIdx.x;           // big tiles first
    const int bh = blockIdx.y;
    const int b = bh >> 4, h = bh & 15;
    const int lane = tid & 63, wq = tid >> 6;
    const int l15 = lane & 15, quad = lane >> 4;
    const size_t tokbase = (size_t)b * 2048;
    const int q0 = qt * 128;

    // ---- stage Q (coalesced, padded) ----
#pragma unroll
    for (int j = 0; j < 4; j++) {
        const int u = tid + j * 256;          // 0..1023 = 128 rows x 8 segs
        const int row = u >> 3, seg = (u & 7) * 8;
        bf16x8 v = *(const bf16x8*)(qb + (tokbase + q0 + row) * 1024 + h * 64 + seg);
        *(bf16x8*)&Qs[row * 72 + seg] = v;
    }
    __syncthreads();
    const bf16x8 aq00 = *(const bf16x8*)&Qs[(wq * 32 + l15) * 72 + quad * 8];        // mi0 ks0
    const bf16x8 aq01 = *(const bf16x8*)&Qs[(wq * 32 + l15) * 72 + 32 + quad * 8];   // mi0 ks1
    const bf16x8 aq10 = *(const bf16x8*)&Qs[(wq * 32 + 16 + l15) * 72 + quad * 8];
    const bf16x8 aq11 = *(const bf16x8*)&Qs[(wq * 32 + 16 + l15) * 72 + 32 + quad * 8];

    // staging geometry: thread covers rows kr and kr+32, one 16B seg each
    const int kr = tid >> 3;                  // 0..31
    const int sg = (tid & 7) * 8;             // elem offset

    bf16x8 pk0, pk1, pv0, pv1;
#define A_GLB(KT) { \
        pk0 = *(const bf16x8*)(kb + (tokbase + (KT) * 64 + kr) * 1024 + h * 64 + sg); \
        pk1 = *(const bf16x8*)(kb + (tokbase + (KT) * 64 + kr + 32) * 1024 + h * 64 + sg); \
        pv0 = *(const bf16x8*)(vT + ((size_t)bh * 64 + kr) * 2048 + (KT) * 64 + sg); \
        pv1 = *(const bf16x8*)(vT + ((size_t)bh * 64 + kr + 32) * 2048 + (KT) * 64 + sg); }

#define A_DECL_Z(mi,n) f32x4 z_##mi##n = {0.f, 0.f, 0.f, 0.f};
    FOR_MN2(A_DECL_Z)

    const int nkt = 2 * qt + 2;
    A_GLB(0)
    for (int kt = 0; kt < nkt; kt++) {
        __syncthreads();                      // prev-iter K/V readers done
        *(bf16x8*)&Ks[kr * 72 + sg] = pk0;
        *(bf16x8*)&Ks[(kr + 32) * 72 + sg] = pk1;
        *(bf16x8*)&Vs[kr * 72 + sg] = pv0;
        *(bf16x8*)&Vs[(kr + 32) * 72 + sg] = pv1;
        __syncthreads();                      // publish tile kt
        if (kt + 1 < nkt) A_GLB(kt + 1)       // prefetch flies during compute

        // S = Q K^T : 32 q-rows x 64 k-cols per wave
#define A_DECL_S(mi,n) f32x4 s_##mi##n = {0.f, 0.f, 0.f, 0.f};
        FOR_MN2(A_DECL_S)
#define A_QKH(KS, AQ0, AQ1) { \
        bf16x8 b0 = *(const bf16x8*)&Ks[(l15) * 72 + (KS) * 32 + quad * 8]; \
        bf16x8 b1 = *(const bf16x8*)&Ks[(16 + l15) * 72 + (KS) * 32 + quad * 8]; \
        bf16x8 b2 = *(const bf16x8*)&Ks[(32 + l15) * 72 + (KS) * 32 + quad * 8]; \
        bf16x8 b3 = *(const bf16x8*)&Ks[(48 + l15) * 72 + (KS) * 32 + quad * 8]; \
        s_00 = __builtin_amdgcn_mfma_f32_16x16x32_bf16(AQ0, b0, s_00, 0, 0, 0); \
        s_01 = __builtin_amdgcn_mfma_f32_16x16x32_bf16(AQ0, b1, s_01, 0, 0, 0); \
        s_02 = __builtin_amdgcn_mfma_f32_16x16x32_bf16(AQ0, b2, s_02, 0, 0, 0); \
        s_03 = __builtin_amdgcn_mfma_f32_16x16x32_bf16(AQ0, b3, s_03, 0, 0, 0); \
        s_10 = __builtin_amdgcn_mfma_f32_16x16x32_bf16(AQ1, b0, s_10, 0, 0, 0); \
        s_11 = __builtin_amdgcn_mfma_f32_16x16x32_bf16(AQ1, b1, s_11, 0, 0, 0); \
        s_12 = __builtin_amdgcn_mfma_f32_16x16x32_bf16(AQ1, b2, s_12, 0, 0, 0); \
        s_13 = __builtin_amdgcn_mfma_f32_16x16x32_bf16(AQ1, b3, s_13, 0, 0, 0); }
        A_QKH(0, aq00, aq10)
        A_QKH(1, aq01, aq11)

        // P = S^2 (q,k carry the 1/8 scale), causal mask on diagonal tiles
        const bool needmask = (kt >= 2 * qt);
#define A_PSTORE(mi,n) { \
        f32x4 p4 = s_##mi##n * s_##mi##n; \
        if (needmask) { _Pragma("unroll") \
            for (int r = 0; r < 4; r++) \
                if (kt * 64 + (n) * 16 + l15 > q0 + wq * 32 + (mi) * 16 + quad * 4 + r) p4[r] = 0.f; } \
        _Pragma("unroll") \
        for (int r = 0; r < 4; r++) \
            Pm[(wq * 32 + (mi) * 16 + quad * 4 + r) * 72 + (n) * 16 + l15] = f2bf(p4[r]); }
        FOR_MN2(A_PSTORE)

        // Z += P @ V
#define A_PVH(KS) { \
        bf16x8 ap0 = *(const bf16x8*)&Pm[(wq * 32 + l15) * 72 + (KS) * 32 + quad * 8]; \
        bf16x8 ap1 = *(const bf16x8*)&Pm[(wq * 32 + 16 + l15) * 72 + (KS) * 32 + quad * 8]; \
        bf16x8 u0 = *(const bf16x8*)&Vs[(l15) * 72 + (KS) * 32 + quad * 8]; \
        bf16x8 u1 = *(const bf16x8*)&Vs[(16 + l15) * 72 + (KS) * 32 + quad * 8]; \
        bf16x8 u2 = *(const bf16x8*)&Vs[(32 + l15) * 72 + (KS) * 32 + quad * 8]; \
        bf16x8 u3 = *(const bf16x8*)&Vs[(48 + l15) * 72 + (KS) * 32 + quad * 8]; \
        z_00 = __builtin_amdgcn_mfma_f32_16x16x32_bf16(ap0, u0, z_00, 0, 0, 0); \
        z_01 = __builtin_amdgcn_mfma_f32_16x16x32_bf16(ap0, u1, z_01, 0, 0, 0); \
        z_02 = __builtin_amdgcn_mfma_f32_16x16x32_bf16(ap0, u2, z_02, 0, 0, 0); \
        z_03 = __builtin_amdgcn_mfma_f32_16x16x32_bf16(ap0, u3, z_03, 0, 0, 0); \
        z_10 = __builtin_amdgcn_mfma_f32_16x16x32_bf16(ap1, u0, z_10, 0, 0, 0); \
        z_11 = __builtin_amdgcn_mfma_f32_16x16x32_bf16(ap1, u1, z_11, 0, 0, 0); \
        z_12 = __builtin_amdgcn_mfma_f32_16x16x32_bf16(ap1, u2, z_12, 0, 0, 0); \
        z_13 = __builtin_amdgcn_mfma_f32_16x16x32_bf16(ap1, u3, z_13, 0, 0, 0); }
        A_PVH(0)
        A_PVH(1)
    }

    // stage z into wave-private Pm rows, then 16B contiguous stores
#define A_ZST(mi,n) { _Pragma("unroll") \
        for (int r = 0; r < 4; r++) \
            Pm[(wq * 32 + (mi) * 16 + quad * 4 + r) * 72 + (n) * 16 + l15] = f2bf(z_##mi##n[r]); }
    FOR_MN2(A_ZST)
#pragma unroll
    for (int it = 0; it < 4; it++) {
        const int linear = it * 64 + lane;
        const int row = linear >> 3, cb = linear & 7;   // 32 rows x 8 segs
        *(bf16x8*)(zb + (tokbase + q0 + wq * 32 + row) * 1024 + h * 64 + cb * 8) =
            *(const bf16x8*)&Pm[(wq * 32 + row) * 72 + cb * 8];
    }
}

// ---------------------------------------------------------------------------
extern "C" void kernel_launch(void* const* d_in, const int* in_sizes, int n_in,
                              void* d_out, int out_size, void* d_ws, size_t ws_size,
                              hipStream_t stream)
{
    const float* x  = (const float*)d_in[0];
    const float* Wq = (const float*)d_in[1];
    const float* bq = (const float*)d_in[2];
    const float* Wk = (const float*)d_in[3];
    const float* bk = (const float*)d_in[4];
    const float* Wv = (const float*)d_in[5];
    const float* bv = (const float*)d_in[6];
    const float* Wo = (const float*)d_in[7];
    const float* nw = (const float*)d_in[8];
    float* out = (float*)d_out;

    const int D = 1024;
    const int M = in_sizes[0] / D;   // B*S = 4096

    unsigned short* xbb = (unsigned short*)d_ws;         // M*D
    unsigned short* Wqb = xbb + (size_t)M * D;           // D*D
    unsigned short* Wkb = Wqb + (size_t)D * D;
    unsigned short* Wvb = Wkb + (size_t)D * D;
    unsigned short* Wob = Wvb + (size_t)D * D;
    unsigned short* qbw = Wob + (size_t)D * D;           // M*D
    unsigned short* kbw = qbw + (size_t)M * D;
    unsigned short* vTw = kbw + (size_t)M * D;
    unsigned short* zbw = vTw + (size_t)M * D;

    const int nx4 = M * D / 4, nw4 = D * D / 4;
    const int ncvt = nx4 + 4 * nw4;
    cvt_all<<<(ncvt + 255) / 256, 256, 0, stream>>>(
        x, Wq, Wk, Wv, Wo, xbb, Wqb, Wkb, Wvb, Wob, nx4, nw4);

    gemm_qkv<<<dim3(D / 128, M / 128, 3), 256, 0, stream>>>(
        xbb, Wqb, Wkb, Wvb, bq, bk, bv, nw, qbw, kbw, vTw, M);

    attn_mfma<<<dim3(16, (M / 2048) * 16), 256, 0, stream>>>(qbw, kbw, vTw, zbw);

    gemm_out<<<dim3(D / 128, M / 128), 256, 0, stream>>>(zbw, Wob, x, out, M);
}